// Round 3
// baseline (367.277 us; speedup 1.0000x reference)
//
#include <hip/hip_runtime.h>
#include <hip/hip_bf16.h>

#define BN   16
#define CN   16
#define HH   512
#define WW   512
#define CIN_ 10
#define HID_ 64
#define Y0_  100
#define X0_  100
#define OS_  300            // cropped output spatial size
#define OPIX (OS_ * OS_)    // 90000 pixels per (b,c) plane

// ---------------------------------------------------------------------------
// Kernel 1: tiny MLP -> theta.  One block, thread t = b*6 + j computes
// out[b][j] = sum_i (b0[i] + sum_k ty[b,k]*W0[i,k]) * W1[j,i] + b1[j]
// then maps to theta = [I + 0.1*out[:, :2] | out[:, 2]].
// All fp32 in / fp32 out (device buffers are fp32; values are bf16-rounded
// upstream by the harness, which is irrelevant to us).
// Writes theta to workspace (for the sampler) and to the d_out tail.
// ---------------------------------------------------------------------------
__global__ void theta_kernel(const float* __restrict__ ty,
                             const float* __restrict__ W0,
                             const float* __restrict__ b0,
                             const float* __restrict__ W1,
                             const float* __restrict__ b1,
                             float* __restrict__ theta_ws,
                             float* __restrict__ theta_out)
{
    int t = threadIdx.x;
    if (t >= BN * 6) return;
    int b = t / 6;
    int j = t - b * 6;

    float tyv[CIN_];
#pragma unroll
    for (int k = 0; k < CIN_; ++k) tyv[k] = ty[b * CIN_ + k];

    float acc = b1[j];
#pragma unroll 4
    for (int i = 0; i < HID_; ++i) {
        float h = b0[i];
#pragma unroll
        for (int k = 0; k < CIN_; ++k) h += tyv[k] * W0[i * CIN_ + k];
        acc += h * W1[j * HID_ + i];
    }

    // theta per batch: row0 = [1+0.1*o0, 0.1*o1, o2], row1 = [0.1*o3, 1+0.1*o4, o5]
    float v;
    if      (j == 0) v = 1.0f + 0.1f * acc;
    else if (j == 1) v = 0.1f * acc;
    else if (j == 2) v = acc;
    else if (j == 3) v = 0.1f * acc;
    else if (j == 4) v = 1.0f + 0.1f * acc;
    else             v = acc;

    theta_ws[t]  = v;
    theta_out[t] = v;
}

// ---------------------------------------------------------------------------
// Kernel 2: fused affine-grid + bilinear grid-sample + crop.
// One thread per output pixel (b, yo, xo); channel loop inside (indices and
// weights shared across all 16 channels). Zero-padding semantics via per-tap
// validity masks, with an all-OOB fast path that skips the gathers entirely.
// ---------------------------------------------------------------------------
__global__ __launch_bounds__(256) void sample_kernel(
    const float* __restrict__ rmap,
    const float* __restrict__ theta,
    float* __restrict__ out)
{
    unsigned gid = blockIdx.x * 256u + threadIdx.x;
    if (gid >= (unsigned)(BN * OPIX)) return;

    unsigned b  = gid / OPIX;
    unsigned p  = gid - b * OPIX;
    unsigned yo = p / OS_;
    unsigned xo = p - yo * OS_;

    int x = (int)xo + X0_;
    int y = (int)yo + Y0_;

    // normalized pixel-center coords: (2*x+1)/W - 1
    float xn = (float)(2 * x + 1) * (1.0f / WW) - 1.0f;
    float yn = (float)(2 * y + 1) * (1.0f / HH) - 1.0f;

    const float* th = theta + b * 6;
    float fx = th[0] * xn + th[1] * yn + th[2];
    float fy = th[3] * xn + th[4] * yn + th[5];

    // source coords: ((f+1)*W - 1) * 0.5
    float ix = (fx + 1.0f) * (0.5f * WW) - 0.5f;
    float iy = (fy + 1.0f) * (0.5f * HH) - 0.5f;

    float ix0f = floorf(ix), iy0f = floorf(iy);
    float wx1 = ix - ix0f,  wy1 = iy - iy0f;
    float wx0 = 1.0f - wx1, wy0 = 1.0f - wy1;

    int ix0 = (int)ix0f, iy0 = (int)iy0f;
    int ix1 = ix0 + 1,   iy1 = iy0 + 1;

    bool vx0 = (ix0 >= 0) & (ix0 < WW);
    bool vx1 = (ix1 >= 0) & (ix1 < WW);
    bool vy0 = (iy0 >= 0) & (iy0 < HH);
    bool vy1 = (iy1 >= 0) & (iy1 < HH);

    float w00 = (vx0 && vy0) ? (wy0 * wx0) : 0.0f;
    float w01 = (vx1 && vy0) ? (wy0 * wx1) : 0.0f;
    float w10 = (vx0 && vy1) ? (wy1 * wx0) : 0.0f;
    float w11 = (vx1 && vy1) ? (wy1 * wx1) : 0.0f;

    unsigned obase = b * (unsigned)(CN * OPIX) + p;

    if (w00 == 0.0f && w01 == 0.0f && w10 == 0.0f && w11 == 0.0f) {
#pragma unroll
        for (int c = 0; c < CN; ++c) out[obase + (unsigned)c * OPIX] = 0.0f;
        return;
    }

    int cx0 = min(max(ix0, 0), WW - 1), cx1 = min(max(ix1, 0), WW - 1);
    int cy0 = min(max(iy0, 0), HH - 1), cy1 = min(max(iy1, 0), HH - 1);

    unsigned o00 = (unsigned)cy0 * WW + cx0;
    unsigned o01 = (unsigned)cy0 * WW + cx1;
    unsigned o10 = (unsigned)cy1 * WW + cx0;
    unsigned o11 = (unsigned)cy1 * WW + cx1;

    const float* img = rmap + (size_t)b * CN * HH * WW;

#pragma unroll
    for (int c = 0; c < CN; ++c) {
        const float* ic = img + (size_t)c * (HH * WW);
        float v = w00 * ic[o00] + w01 * ic[o01]
                + w10 * ic[o10] + w11 * ic[o11];
        out[obase + (unsigned)c * OPIX] = v;
    }
}

extern "C" void kernel_launch(void* const* d_in, const int* in_sizes, int n_in,
                              void* d_out, int out_size, void* d_ws, size_t ws_size,
                              hipStream_t stream)
{
    const float* ty   = (const float*)d_in[0];
    const float* rmap = (const float*)d_in[1];
    const float* W0   = (const float*)d_in[2];
    const float* b0   = (const float*)d_in[3];
    const float* W1   = (const float*)d_in[4];
    const float* b1   = (const float*)d_in[5];

    float* out      = (float*)d_out;
    float* theta_out = out + (size_t)BN * CN * OPIX;  // theta after samp
    float* theta_ws = (float*)d_ws;

    theta_kernel<<<1, 128, 0, stream>>>(ty, W0, b0, W1, b1, theta_ws, theta_out);

    int total  = BN * OPIX;
    int blocks = (total + 255) / 256;
    sample_kernel<<<blocks, 256, 0, stream>>>(rmap, theta_ws, out);
}